// Round 13
// baseline (7175.758 us; speedup 1.0000x reference)
//
#include <hip/hip_runtime.h>
#include <hip/hip_bf16.h>
#include <stdint.h>

typedef __hip_bfloat16 bf16_t;
typedef __attribute__((ext_vector_type(8))) short bf16x8;
typedef __attribute__((ext_vector_type(4))) float f32x4;

#define MU_DT 0.01f

__device__ inline void gload_lds16(const void* g, void* lds) {
  __builtin_amdgcn_global_load_lds((const __attribute__((address_space(1))) void*)g,
                                   (__attribute__((address_space(3))) void*)lds, 16, 0, 0);
}

// mode: 0 = forward tanh layer, 1 = forward identity (last) layer,
//       2 = backward layer 0 (e0 == mu0), 3 = backward layer >0
struct GemmLayer {
  const bf16_t* A;    // (512 x K) bf16, row-major
  const bf16_t* Bt;   // (N x K) bf16, row-major
  const float*  X;    // epilogue input (mu_{l+1}/img fwd; mu_l bwd)
  const float*  E;    // bwd l>0: e_l
  float*        O1;   // fwd: e out (stride ostride); bwd: mu out (f32)
  bf16_t*       O2;   // fwd: G out; bwd: mub out
  float*        P;    // partial base; split s at P + s*512*N  (f32, [512][N])
  int*          cnt;  // per-tile arrival counters (this layer)
  int K, N, ostride, mode;
};

struct Seg { int start; int layer; int split; int tilesN; };

struct GemmArgs {
  GemmLayer L[3];
  Seg seg[7];   // ascending starts; last is sentinel (1<<30)
};

// R13: 128x128 tile, BK=64, 8 waves, SPLIT-K=2 + last-block combine.
// Model (fits R2/R4/R8/R10/R12 + guide m97): perf ~ FLOP/staged-byte x
// staging-rate(waves). 128^2 gives 64 FLOP/B (vs 43.7 at 64x128) but alone
// is grid-starved (R12: 352 blocks, 6.4 waves/CU). Split-K=2 doubles the
// grid (704/576 blocks, 2.75/2.25 per CU at 2/CU LDS cap) with NO operand
// re-duplication. Each split writes an f32 partial; both atomicAdd a
// per-tile counter after __threadfence; the second arrival (old==1)
// re-reads both partials, applies the fused epilogue, resets the counter
// (self-cleaning -> idempotent across graph replays; p0+p1 fixed order ->
// deterministic).
// Engine = R8 verbatim: issue next-tile gload_lds FIRST, ds_read+MFMA on
// current half, ONE __syncthreads per K-step. A through LDS (R11 lesson).
// Grid: seg starts all =0 mod 8, tn FASTEST, tilesN mult of 8 -> B-panel
// sharers land on one XCD (R5 regression guard).
__global__ __launch_bounds__(512) void gemm_merged(GemmArgs args) {
  __shared__ __align__(16) bf16_t As[2 * 128 * 64];   // 2 x 16 KiB
  __shared__ __align__(16) bf16_t Bs[2 * 128 * 64];   // 2 x 16 KiB
  __shared__ int lastFlag;

  const int bid = blockIdx.x;
  int s = 0;
#pragma unroll
  for (int i = 1; i < 7; ++i)
    if (bid >= args.seg[i].start) s = i;
  const Seg sg = args.seg[s];
  const GemmLayer Lr = args.L[sg.layer];
  const int local = bid - sg.start;
  const int tm = local / sg.tilesN;
  const int tn = local % sg.tilesN;
  const int K = Lr.K;
  const int kOff = sg.split * (K >> 1);
  const int rowBase = tm * 128;
  const int colBase = tn * 128;

  const int tid  = threadIdx.x;        // 0..511
  const int lane = tid & 63;
  const int wv   = tid >> 6;           // 0..7
  const int wrM  = wv >> 2;            // 0..1 -> 64-row band
  const int wcN  = wv & 3;             // 0..3 -> 32-col band
  const int lo   = lane & 15, hi = lane >> 4;

  f32x4 acc[4][2];
#pragma unroll
  for (int m = 0; m < 4; ++m)
#pragma unroll
    for (int n = 0; n < 2; ++n)
      acc[m][n] = f32x4{0.f, 0.f, 0.f, 0.f};

  char* AsB = (char*)As;   // halves at +0 / +16384
  char* BsB = (char*)Bs;

  // ---- staging precompute: per 16B-chunk c -> (row = c>>3, slot = c&7) ----
  const bf16_t* pA[2];
  const bf16_t* pB[2];
#pragma unroll
  for (int j = 0; j < 2; ++j) {
    const int c = j * 512 + tid;
    const int r = c >> 3, sw = (c & 7) ^ (r & 7);
    pA[j] = Lr.A  + (size_t)(rowBase + r) * K + kOff + sw * 8;
    pB[j] = Lr.Bt + (size_t)(colBase + r) * K + kOff + sw * 8;
  }

  // ---- read-side swizzled byte offsets (16-lane cohorts, conflict-free) ----
  int aoff[4][2], boff[2][2];
#pragma unroll
  for (int m = 0; m < 4; ++m) {
    const int row = wrM * 64 + m * 16 + lo;
#pragma unroll
    for (int kk = 0; kk < 2; ++kk)
      aoff[m][kk] = row * 128 + (((kk * 4 + hi) ^ (row & 7)) << 4);
  }
#pragma unroll
  for (int n = 0; n < 2; ++n) {
    const int row = wcN * 32 + n * 16 + lo;
#pragma unroll
    for (int kk = 0; kk < 2; ++kk)
      boff[n][kk] = row * 128 + (((kk * 4 + hi) ^ (row & 7)) << 4);
  }

  const int waveB = wv * 1024;
  const int nkt = K >> 7;   // K/2 worth of BK=64 steps (8..32)

  // prologue: stage tile 0 into half 0
#pragma unroll
  for (int j = 0; j < 2; ++j) {
    gload_lds16(pA[j], AsB + j * 8192 + waveB);
    gload_lds16(pB[j], BsB + j * 8192 + waveB);
  }
  __syncthreads();

  int cur = 0;
  for (int kt = 0; kt < nkt; ++kt) {
    if (kt + 1 < nkt) {
      const int ke = (kt + 1) * 64;
      const int nxt = cur ^ 16384;
#pragma unroll
      for (int j = 0; j < 2; ++j) {
        gload_lds16(pA[j] + ke, AsB + nxt + j * 8192 + waveB);
        gload_lds16(pB[j] + ke, BsB + nxt + j * 8192 + waveB);
      }
    }

    bf16x8 a[4][2], b[2][2];
#pragma unroll
    for (int m = 0; m < 4; ++m)
#pragma unroll
      for (int kk = 0; kk < 2; ++kk)
        a[m][kk] = *(const bf16x8*)(AsB + cur + aoff[m][kk]);
#pragma unroll
    for (int n = 0; n < 2; ++n)
#pragma unroll
      for (int kk = 0; kk < 2; ++kk)
        b[n][kk] = *(const bf16x8*)(BsB + cur + boff[n][kk]);

#pragma unroll
    for (int kk = 0; kk < 2; ++kk)
#pragma unroll
      for (int m = 0; m < 4; ++m)
#pragma unroll
        for (int n = 0; n < 2; ++n)
          acc[m][n] = __builtin_amdgcn_mfma_f32_16x16x32_bf16(a[m][kk], b[n][kk], acc[m][n], 0, 0, 0);

    if (kt + 1 < nkt) {
      __syncthreads();
      cur ^= 16384;
    }
  }

  // ---- write this split's partial (f32) ----
  const int N = Lr.N;
  float* Pp = Lr.P + (size_t)sg.split * 512 * N;
#pragma unroll
  for (int m = 0; m < 4; ++m) {
#pragma unroll
    for (int n = 0; n < 2; ++n) {
#pragma unroll
      for (int r = 0; r < 4; ++r) {
        const int row = rowBase + wrM * 64 + m * 16 + hi * 4 + r;
        const int col = colBase + wcN * 32 + n * 16 + lo;
        Pp[(size_t)row * N + col] = acc[m][n][r];
      }
    }
  }
  __syncthreads();   // all partial stores complete (vmcnt drain)

  // ---- arrival counter: second arrival combines ----
  if (tid == 0) {
    __threadfence();   // make partial visible device-wide before counting
    const int old = atomicAdd(&Lr.cnt[tm * sg.tilesN + tn], 1);
    lastFlag = (old == 1);
    if (old == 1) Lr.cnt[tm * sg.tilesN + tn] = 0;   // self-reset for next use
  }
  __syncthreads();
  if (!lastFlag) return;

  __threadfence();   // acquire: see the other split's partial
  const float* P0 = Lr.P;
  const float* P1 = Lr.P + (size_t)512 * N;

  // combine + fused epilogue over the 128x128 tile; f32x4 per chunk
  for (int c = tid; c < 128 * 32; c += 512) {
    const int row = rowBase + (c >> 5);
    const int col = colBase + ((c & 31) << 2);
    const size_t iN = (size_t)row * N + col;
    const size_t iO = (size_t)row * Lr.ostride + col;
    const f32x4 v4 = *(const f32x4*)(P0 + iN) + *(const f32x4*)(P1 + iN);
    if (Lr.mode == 0) {
      const f32x4 mu = *(const f32x4*)(Lr.X + iN);
      f32x4 e4; float g4[4];
#pragma unroll
      for (int j = 0; j < 4; ++j) {
        const float t = tanhf(v4[j]);
        e4[j] = mu[j] - t;
        g4[j] = e4[j] * (1.0f - t * t);
      }
      *(f32x4*)(Lr.O1 + iO) = e4;
#pragma unroll
      for (int j = 0; j < 4; ++j) Lr.O2[iN + j] = __float2bfloat16(g4[j]);
    } else if (Lr.mode == 1) {
      const f32x4 mu = *(const f32x4*)(Lr.X + iN);
      const f32x4 e4 = mu - v4;
      *(f32x4*)(Lr.O1 + iO) = e4;
#pragma unroll
      for (int j = 0; j < 4; ++j) Lr.O2[iN + j] = __float2bfloat16(e4[j]);
    } else if (Lr.mode == 2) {
      const f32x4 mu = *(const f32x4*)(Lr.X + iN);
      f32x4 nv;
#pragma unroll
      for (int j = 0; j < 4; ++j) nv[j] = mu[j] + MU_DT * (v4[j] - mu[j]);
      *(f32x4*)(Lr.O1 + iN) = nv;
#pragma unroll
      for (int j = 0; j < 4; ++j) Lr.O2[iN + j] = __float2bfloat16(nv[j]);
    } else {
      const f32x4 mu = *(const f32x4*)(Lr.X + iN);
      const f32x4 e  = *(const f32x4*)(Lr.E + iN);
      f32x4 nv;
#pragma unroll
      for (int j = 0; j < 4; ++j) nv[j] = mu[j] + MU_DT * (v4[j] - e[j]);
      *(f32x4*)(Lr.O1 + iN) = nv;
#pragma unroll
      for (int j = 0; j < 4; ++j) Lr.O2[iN + j] = __float2bfloat16(nv[j]);
    }
  }
}

__global__ void zero_cnt(int* c, int n) {
  const int i = blockIdx.x * blockDim.x + threadIdx.x;
  if (i < n) c[i] = 0;
}

// convert W (R x C f32) -> Wb (R x C bf16) and WTb (C x R bf16)
__global__ void prep_weight(const float* __restrict__ W, bf16_t* __restrict__ Wb,
                            bf16_t* __restrict__ WTb, int R, int C) {
  __shared__ bf16_t t[64][65];
  const int tx = threadIdx.x, ty = threadIdx.y;  // (64,4)
  const int c0 = blockIdx.x * 64, r0 = blockIdx.y * 64;
  for (int rr = ty; rr < 64; rr += 4) {
    const float v = W[(size_t)(r0 + rr) * C + c0 + tx];
    const bf16_t b = __float2bfloat16(v);
    Wb[(size_t)(r0 + rr) * C + c0 + tx] = b;
    t[rr][tx] = b;
  }
  __syncthreads();
  for (int rr = ty; rr < 64; rr += 4) {
    WTb[(size_t)(c0 + rr) * R + r0 + tx] = t[tx][rr];
  }
}

__global__ void copy_cast(const float* __restrict__ in, float* __restrict__ of,
                          bf16_t* __restrict__ ob, int n) {
  const int i = blockIdx.x * blockDim.x + threadIdx.x;
  if (i < n) {
    const float v = in[i];
    of[i] = v;
    ob[i] = __float2bfloat16(v);
  }
}

__global__ void copy_e0(const float* __restrict__ mu0, float* __restrict__ out) {
  const int i = blockIdx.x * blockDim.x + threadIdx.x;
  if (i < 512 * 1024) {
    const int b = i >> 10, j = i & 1023;
    out[(size_t)b * 12288 + j] = mu0[i];
  }
}

extern "C" void kernel_launch(void* const* d_in, const int* in_sizes, int n_in,
                              void* d_out, int out_size, void* d_ws, size_t ws_size,
                              hipStream_t stream) {
  const float* img  = (const float*)d_in[0];
  const float* mu0i = (const float*)d_in[1];
  const float* mu1i = (const float*)d_in[2];
  const float* mu2i = (const float*)d_in[3];
  const float* W0   = (const float*)d_in[4];
  const float* W1   = (const float*)d_in[5];
  const float* W2   = (const float*)d_in[6];
  float* out = (float*)d_out;
  const int n_iters = 20;  // fixed by setup_inputs

  // ---- workspace carve (all offsets 256B aligned) ----
  char* p = (char*)d_ws;
  auto alloc = [&](size_t bytes) -> char* {
    char* r = p;
    p += (bytes + 255) & ~(size_t)255;
    return r;
  };
  bf16_t* Wb0 = (bf16_t*)alloc((size_t)1024 * 4096 * 2);
  bf16_t* Wb1 = (bf16_t*)alloc((size_t)4096 * 4096 * 2);
  bf16_t* Wb2 = (bf16_t*)alloc((size_t)4096 * 3072 * 2);
  bf16_t* WT0 = (bf16_t*)alloc((size_t)4096 * 1024 * 2);
  bf16_t* WT1 = (bf16_t*)alloc((size_t)4096 * 4096 * 2);
  bf16_t* WT2 = (bf16_t*)alloc((size_t)3072 * 4096 * 2);
  float*  mu0 = (float*)alloc((size_t)512 * 1024 * 4);
  float*  mu1 = (float*)alloc((size_t)512 * 4096 * 4);
  float*  mu2 = (float*)alloc((size_t)512 * 4096 * 4);
  bf16_t* mb0 = (bf16_t*)alloc((size_t)512 * 1024 * 2);
  bf16_t* mb1 = (bf16_t*)alloc((size_t)512 * 4096 * 2);
  bf16_t* mb2 = (bf16_t*)alloc((size_t)512 * 4096 * 2);
  float*  e1  = (float*)alloc((size_t)512 * 4096 * 4);
  float*  e2  = (float*)alloc((size_t)512 * 4096 * 4);
  float*  e3  = (float*)alloc((size_t)512 * 3072 * 4);
  bf16_t* G0  = (bf16_t*)alloc((size_t)512 * 4096 * 2);
  bf16_t* G1  = (bf16_t*)alloc((size_t)512 * 4096 * 2);
  bf16_t* G2  = (bf16_t*)alloc((size_t)512 * 3072 * 2);
  // split-K partials (shared by fwd/bwd dispatches; each layer region 2x512xN)
  float* P0r = (float*)alloc((size_t)2 * 512 * 4096 * 4);
  float* P1r = (float*)alloc((size_t)2 * 512 * 4096 * 4);
  float* P2r = (float*)alloc((size_t)2 * 512 * 4096 * 4);
  int*   cnt = (int*)alloc((size_t)1024 * 4);   // fwd 352 @0, bwd 288 @352
  (void)ws_size;

  // ---- prep: counters, weights, mus ----
  zero_cnt<<<4, 256, 0, stream>>>(cnt, 1024);
  dim3 tb(64, 4);
  prep_weight<<<dim3(4096 / 64, 1024 / 64), tb, 0, stream>>>(W0, Wb0, WT0, 1024, 4096);
  prep_weight<<<dim3(4096 / 64, 4096 / 64), tb, 0, stream>>>(W1, Wb1, WT1, 4096, 4096);
  prep_weight<<<dim3(3072 / 64, 4096 / 64), tb, 0, stream>>>(W2, Wb2, WT2, 4096, 3072);
  copy_cast<<<(512 * 1024 + 255) / 256, 256, 0, stream>>>(mu0i, mu0, mb0, 512 * 1024);
  copy_cast<<<(512 * 4096 + 255) / 256, 256, 0, stream>>>(mu1i, mu1, mb1, 512 * 4096);
  copy_cast<<<(512 * 4096 + 255) / 256, 256, 0, stream>>>(mu2i, mu2, mb2, 512 * 4096);

  int* cntF = cnt;        // L0 @0 (128), L1 @128 (128), L2 @256 (96)
  int* cntB = cnt + 352;  // L0 @0 (32),  L1 @32 (128),  L2 @160 (128)

  // ---- forward: h_l = mu_l @ W_l (split-K=2) ----
  GemmArgs fa;
  fa.L[0] = { mb0, WT0, mu1, nullptr, e1, G0, P0r, cntF,       1024, 4096, 4096, 0 };
  fa.L[1] = { mb1, WT1, mu2, nullptr, e2, G1, P1r, cntF + 128, 4096, 4096, 4096, 0 };
  fa.L[2] = { mb2, WT2, img, nullptr, e3, G2, P2r, cntF + 256, 4096, 3072, 3072, 1 };
  // heavy-first: L1s0, L1s1, L2s0, L2s1, L0s0, L0s1  (starts all %8==0)
  fa.seg[0] = { 0,   1, 0, 32 };
  fa.seg[1] = { 128, 1, 1, 32 };
  fa.seg[2] = { 256, 2, 0, 24 };
  fa.seg[3] = { 352, 2, 1, 24 };
  fa.seg[4] = { 448, 0, 0, 32 };
  fa.seg[5] = { 576, 0, 1, 32 };
  fa.seg[6] = { 1 << 30, 0, 0, 1 };
  const int fwdBlocks = 704;

  GemmArgs faF = fa;  // final pass: errs straight into d_out (stride 12288)
  faF.L[0].O1 = out + 1024; faF.L[0].ostride = 12288;
  faF.L[1].O1 = out + 5120; faF.L[1].ostride = 12288;
  faF.L[2].O1 = out + 9216; faF.L[2].ostride = 12288;

  // ---- backward: back_l = G_l @ W_l^T (split-K=2) ----
  GemmArgs ba;
  ba.L[0] = { G0, Wb0, mu0, nullptr, mu0, mb0, P0r, cntB,       4096, 1024, 1024, 2 };
  ba.L[1] = { G1, Wb1, mu1, e1,      mu1, mb1, P1r, cntB + 32,  4096, 4096, 4096, 3 };
  ba.L[2] = { G2, Wb2, mu2, e2,      mu2, mb2, P2r, cntB + 160, 3072, 4096, 4096, 3 };
  ba.seg[0] = { 0,   1, 0, 32 };
  ba.seg[1] = { 128, 1, 1, 32 };
  ba.seg[2] = { 256, 2, 0, 32 };
  ba.seg[3] = { 384, 2, 1, 32 };
  ba.seg[4] = { 512, 0, 0, 8 };
  ba.seg[5] = { 544, 0, 1, 8 };
  ba.seg[6] = { 1 << 30, 0, 0, 1 };
  const int bwdBlocks = 576;

  // ---- iterate ----
  for (int it = 0; it < n_iters; ++it) {
    gemm_merged<<<fwdBlocks, 512, 0, stream>>>(fa);
    gemm_merged<<<bwdBlocks, 512, 0, stream>>>(ba);
  }
  // final prediction/error pass + e0 = mu0
  gemm_merged<<<fwdBlocks, 512, 0, stream>>>(faF);
  copy_e0<<<(512 * 1024 + 255) / 256, 256, 0, stream>>>(mu0, out);
}

// Round 15
// 2501.751 us; speedup vs baseline: 2.8683x; 2.8683x over previous
//
#include <hip/hip_runtime.h>
#include <hip/hip_bf16.h>
#include <stdint.h>

typedef __hip_bfloat16 bf16_t;
typedef __attribute__((ext_vector_type(8))) short bf16x8;
typedef __attribute__((ext_vector_type(4))) float f32x4;

#define MU_DT 0.01f

__device__ inline void gload_lds16(const void* g, void* lds) {
  __builtin_amdgcn_global_load_lds((const __attribute__((address_space(1))) void*)g,
                                   (__attribute__((address_space(3))) void*)lds, 16, 0, 0);
}

// mode: 0 = forward tanh layer, 1 = forward identity (last) layer,
//       2 = backward layer 0 (e0 == mu0), 3 = backward layer >0
struct GemmLayer {
  const bf16_t* A;    // (512 x K) bf16, row-major
  const bf16_t* Bt;   // (N x K) bf16, row-major  ("B^T layout" operand)
  const float*  X;    // fwd: mu_{l+1} or img (512 x N); bwd: mu_l (512 x N)
  const float*  E;    // bwd l>0: e_l (512 x N); else unused
  float*        O1;   // fwd: e_{l+1} out (stride ostride); bwd: mu_l out (f32)
  bf16_t*       O2;   // fwd: G_l out (bf16, 512 x N); bwd: mub_l out (bf16)
  int K, N, ostride, mode;
};

struct Seg { int start, layer, tmBase, tilesN; };

struct GemmArgs {
  GemmLayer L[3];
  Seg seg[8];   // ascending starts; unused = sentinel 1<<30
};

// R15 = R8 engine (best known, 2543us) + MAKESPAN-BALANCED job tables.
// Engine: BM=64 x BN=128, BK=64, 8 waves (512 thr), wave 32x32 of
// 16x16x32 MFMA, dbuf 48KiB, issue-next-tile gload_lds FIRST then
// ds_read+MFMA then ONE __syncthreads per K-step. A through LDS.
//
// Balance theory: grids (704/576) <= capacity (3 blk/CU @48KiB) => all
// blocks resident from t=0; CU c hosts blocks {c, c+256, c+512} (same-XCD:
// (c+256)/8%32 == c/8%32). Makespan = max per-CU step-sum.
// R8 bwd order gave CUs c<64: L0(64)+L1(64)+L2(48)=176 steps vs 112 for
// the rest. Rebalanced: c<64: L2+L2+L2=144; c in [64,192): L1+L1=128;
// c>=192: L2+L0=112 -> makespan 176->144 (-18% bwd).
// Fwd already optimal at 128 (=64+48+16, forced by quanta); unchanged.
//
// Grid mapping guard (R5): seg starts all %8==0, tilesN mult of 8, tn
// fastest -> B-panel sharers congruent mod 8 -> same XCD L2.
__global__ __launch_bounds__(512) void gemm_merged(GemmArgs args) {
  __shared__ __align__(16) bf16_t As[2 * 64 * 64];    // 2 x 8 KiB
  __shared__ __align__(16) bf16_t Bs[2 * 128 * 64];   // 2 x 16 KiB

  const int bid = blockIdx.x;
  int s = 0;
#pragma unroll
  for (int i = 1; i < 8; ++i)
    if (bid >= args.seg[i].start) s = i;
  const Seg sg = args.seg[s];
  const GemmLayer Lr = args.L[sg.layer];
  const int local = bid - sg.start;
  const int tm = sg.tmBase + local / sg.tilesN;
  const int tn = local % sg.tilesN;
  const int K = Lr.K;
  const int rowBase = tm * 64;
  const int colBase = tn * 128;

  const int tid  = threadIdx.x;        // 0..511
  const int lane = tid & 63;
  const int wv   = tid >> 6;           // 0..7
  const int wrM  = wv >> 2;            // 0..1 -> 32-row band
  const int wcN  = wv & 3;             // 0..3 -> 32-col band
  const int lo   = lane & 15, hi = lane >> 4;

  f32x4 acc[2][2];
#pragma unroll
  for (int m = 0; m < 2; ++m)
#pragma unroll
    for (int n = 0; n < 2; ++n)
      acc[m][n] = f32x4{0.f, 0.f, 0.f, 0.f};

  char* AsB = (char*)As;   // halves at +0 / +8192
  char* BsB = (char*)Bs;   // halves at +0 / +16384

  // ---- staging precompute: per 16B-chunk c -> (row = c>>3, slot = c&7) ----
  // A tile: 64x64 bf16 = 512 chunks (1/thread). B tile: 1024 chunks (2/thread).
  const bf16_t* pA0;
  const bf16_t* pB[2];
  {
    const int c = tid;
    const int r = c >> 3, sw = (c & 7) ^ (r & 7);
    pA0 = Lr.A + (size_t)(rowBase + r) * K + sw * 8;
  }
#pragma unroll
  for (int j = 0; j < 2; ++j) {
    const int c = j * 512 + tid;
    const int r = c >> 3, sw = (c & 7) ^ (r & 7);
    pB[j] = Lr.Bt + (size_t)(colBase + r) * K + sw * 8;
  }

  // ---- read-side swizzled byte offsets ----
  int aoff[2][2], boff[2][2];
#pragma unroll
  for (int m = 0; m < 2; ++m) {
    const int row = wrM * 32 + m * 16 + lo;
#pragma unroll
    for (int kk = 0; kk < 2; ++kk)
      aoff[m][kk] = row * 128 + (((kk * 4 + hi) ^ (row & 7)) << 4);
  }
#pragma unroll
  for (int n = 0; n < 2; ++n) {
    const int row = wcN * 32 + n * 16 + lo;
#pragma unroll
    for (int kk = 0; kk < 2; ++kk)
      boff[n][kk] = row * 128 + (((kk * 4 + hi) ^ (row & 7)) << 4);
  }

  const int waveB = wv * 1024;
  const int nkt = K >> 6;

  // prologue: stage tile 0 into half 0 (3 loads/thread: 1 A + 2 B)
  gload_lds16(pA0,   AsB + waveB);
  gload_lds16(pB[0], BsB + waveB);
  gload_lds16(pB[1], BsB + 8192 + waveB);
  __syncthreads();

  int cur = 0;   // 0 / 1
  for (int kt = 0; kt < nkt; ++kt) {
    const int curA = cur * 8192, curB = cur * 16384;
    if (kt + 1 < nkt) {
      const int ke = (kt + 1) * 64;
      gload_lds16(pA0 + ke,   AsB + (curA ^ 8192) + waveB);
      gload_lds16(pB[0] + ke, BsB + (curB ^ 16384) + waveB);
      gload_lds16(pB[1] + ke, BsB + (curB ^ 16384) + 8192 + waveB);
    }

    bf16x8 a[2][2], b[2][2];
#pragma unroll
    for (int m = 0; m < 2; ++m)
#pragma unroll
      for (int kk = 0; kk < 2; ++kk)
        a[m][kk] = *(const bf16x8*)(AsB + curA + aoff[m][kk]);
#pragma unroll
    for (int n = 0; n < 2; ++n)
#pragma unroll
      for (int kk = 0; kk < 2; ++kk)
        b[n][kk] = *(const bf16x8*)(BsB + curB + boff[n][kk]);

#pragma unroll
    for (int kk = 0; kk < 2; ++kk)
#pragma unroll
      for (int m = 0; m < 2; ++m)
#pragma unroll
        for (int n = 0; n < 2; ++n)
          acc[m][n] = __builtin_amdgcn_mfma_f32_16x16x32_bf16(a[m][kk], b[n][kk], acc[m][n], 0, 0, 0);

    if (kt + 1 < nkt) {
      __syncthreads();   // drains vmcnt (next tile) + lgkm; one barrier per K-step
      cur ^= 1;
    }
  }

  // epilogue — C/D layout: col = lane&15, row = (lane>>4)*4 + reg
  const int N = Lr.N;
#pragma unroll
  for (int m = 0; m < 2; ++m) {
#pragma unroll
    for (int n = 0; n < 2; ++n) {
#pragma unroll
      for (int r = 0; r < 4; ++r) {
        const int row = rowBase + wrM * 32 + m * 16 + hi * 4 + r;
        const int col = colBase + wcN * 32 + n * 16 + lo;
        const float v = acc[m][n][r];
        const size_t iN = (size_t)row * N + col;
        const size_t iO = (size_t)row * Lr.ostride + col;
        if (Lr.mode == 0) {
          const float mu = Lr.X[iN];
          const float t  = tanhf(v);
          const float e  = mu - t;
          Lr.O1[iO] = e;
          Lr.O2[iN] = __float2bfloat16(e * (1.0f - t * t));
        } else if (Lr.mode == 1) {
          const float e = Lr.X[iN] - v;
          Lr.O1[iO] = e;
          Lr.O2[iN] = __float2bfloat16(e);
        } else if (Lr.mode == 2) {
          const float mu = Lr.X[iN];
          const float nv = mu + MU_DT * (v - mu);
          Lr.O1[iN] = nv;
          Lr.O2[iN] = __float2bfloat16(nv);
        } else {
          const float mu = Lr.X[iN];
          const float e  = Lr.E[iN];
          const float nv = mu + MU_DT * (v - e);
          Lr.O1[iN] = nv;
          Lr.O2[iN] = __float2bfloat16(nv);
        }
      }
    }
  }
}

// convert W (R x C f32) -> Wb (R x C bf16) and WTb (C x R bf16)
__global__ void prep_weight(const float* __restrict__ W, bf16_t* __restrict__ Wb,
                            bf16_t* __restrict__ WTb, int R, int C) {
  __shared__ bf16_t t[64][65];
  const int tx = threadIdx.x, ty = threadIdx.y;  // (64,4)
  const int c0 = blockIdx.x * 64, r0 = blockIdx.y * 64;
  for (int rr = ty; rr < 64; rr += 4) {
    const float v = W[(size_t)(r0 + rr) * C + c0 + tx];
    const bf16_t b = __float2bfloat16(v);
    Wb[(size_t)(r0 + rr) * C + c0 + tx] = b;
    t[rr][tx] = b;
  }
  __syncthreads();
  for (int rr = ty; rr < 64; rr += 4) {
    WTb[(size_t)(c0 + rr) * R + r0 + tx] = t[tx][rr];
  }
}

__global__ void copy_cast(const float* __restrict__ in, float* __restrict__ of,
                          bf16_t* __restrict__ ob, int n) {
  const int i = blockIdx.x * blockDim.x + threadIdx.x;
  if (i < n) {
    const float v = in[i];
    of[i] = v;
    ob[i] = __float2bfloat16(v);
  }
}

__global__ void copy_e0(const float* __restrict__ mu0, float* __restrict__ out) {
  const int i = blockIdx.x * blockDim.x + threadIdx.x;
  if (i < 512 * 1024) {
    const int b = i >> 10, j = i & 1023;
    out[(size_t)b * 12288 + j] = mu0[i];
  }
}

extern "C" void kernel_launch(void* const* d_in, const int* in_sizes, int n_in,
                              void* d_out, int out_size, void* d_ws, size_t ws_size,
                              hipStream_t stream) {
  const float* img  = (const float*)d_in[0];
  const float* mu0i = (const float*)d_in[1];
  const float* mu1i = (const float*)d_in[2];
  const float* mu2i = (const float*)d_in[3];
  const float* W0   = (const float*)d_in[4];
  const float* W1   = (const float*)d_in[5];
  const float* W2   = (const float*)d_in[6];
  float* out = (float*)d_out;
  const int n_iters = 20;  // fixed by setup_inputs

  // ---- workspace carve (all offsets 256B aligned) ----
  char* p = (char*)d_ws;
  auto alloc = [&](size_t bytes) -> char* {
    char* r = p;
    p += (bytes + 255) & ~(size_t)255;
    return r;
  };
  bf16_t* Wb0 = (bf16_t*)alloc((size_t)1024 * 4096 * 2);
  bf16_t* Wb1 = (bf16_t*)alloc((size_t)4096 * 4096 * 2);
  bf16_t* Wb2 = (bf16_t*)alloc((size_t)4096 * 3072 * 2);
  bf16_t* WT0 = (bf16_t*)alloc((size_t)4096 * 1024 * 2);
  bf16_t* WT1 = (bf16_t*)alloc((size_t)4096 * 4096 * 2);
  bf16_t* WT2 = (bf16_t*)alloc((size_t)3072 * 4096 * 2);
  float*  mu0 = (float*)alloc((size_t)512 * 1024 * 4);
  float*  mu1 = (float*)alloc((size_t)512 * 4096 * 4);
  float*  mu2 = (float*)alloc((size_t)512 * 4096 * 4);
  bf16_t* mb0 = (bf16_t*)alloc((size_t)512 * 1024 * 2);
  bf16_t* mb1 = (bf16_t*)alloc((size_t)512 * 4096 * 2);
  bf16_t* mb2 = (bf16_t*)alloc((size_t)512 * 4096 * 2);
  float*  e1  = (float*)alloc((size_t)512 * 4096 * 4);
  float*  e2  = (float*)alloc((size_t)512 * 4096 * 4);
  float*  e3  = (float*)alloc((size_t)512 * 3072 * 4);
  bf16_t* G0  = (bf16_t*)alloc((size_t)512 * 4096 * 2);
  bf16_t* G1  = (bf16_t*)alloc((size_t)512 * 4096 * 2);
  bf16_t* G2  = (bf16_t*)alloc((size_t)512 * 3072 * 2);
  (void)ws_size;

  // ---- prep: weights + mus ----
  dim3 tb(64, 4);
  prep_weight<<<dim3(4096 / 64, 1024 / 64), tb, 0, stream>>>(W0, Wb0, WT0, 1024, 4096);
  prep_weight<<<dim3(4096 / 64, 4096 / 64), tb, 0, stream>>>(W1, Wb1, WT1, 4096, 4096);
  prep_weight<<<dim3(3072 / 64, 4096 / 64), tb, 0, stream>>>(W2, Wb2, WT2, 4096, 3072);
  copy_cast<<<(512 * 1024 + 255) / 256, 256, 0, stream>>>(mu0i, mu0, mb0, 512 * 1024);
  copy_cast<<<(512 * 4096 + 255) / 256, 256, 0, stream>>>(mu1i, mu1, mb1, 512 * 4096);
  copy_cast<<<(512 * 4096 + 255) / 256, 256, 0, stream>>>(mu2i, mu2, mb2, 512 * 4096);

  const Seg SENT = { 1 << 30, 0, 0, 1 };

  // ---- forward (R8 layout, makespan 128 = forced optimum) ----
  // CU c<192: L0(16)+L1(64)+L2(48)=128; c>=192: L0+L1=80.
  GemmArgs fa;
  fa.L[0] = { mb0, WT0, mu1, nullptr, e1, G0, 1024, 4096, 4096, 0 };
  fa.L[1] = { mb1, WT1, mu2, nullptr, e2, G1, 4096, 4096, 4096, 0 };
  fa.L[2] = { mb2, WT2, img, nullptr, e3, G2, 4096, 3072, 3072, 1 };
  fa.seg[0] = { 0,   0, 0, 32 };   // L0: 256 jobs (16 steps)
  fa.seg[1] = { 256, 1, 0, 32 };   // L1: 256 jobs (64 steps)
  fa.seg[2] = { 512, 2, 0, 24 };   // L2: 192 jobs (48 steps)
  fa.seg[3] = SENT; fa.seg[4] = SENT; fa.seg[5] = SENT;
  fa.seg[6] = SENT; fa.seg[7] = SENT;
  const int fwdBlocks = 704;

  GemmArgs faF = fa;  // final pass: errs straight into d_out (stride 12288)
  faF.L[0].O1 = out + 1024; faF.L[0].ostride = 12288;
  faF.L[1].O1 = out + 5120; faF.L[1].ostride = 12288;
  faF.L[2].O1 = out + 9216; faF.L[2].ostride = 12288;

  // ---- backward (REBALANCED: makespan 176 -> 144) ----
  // quanta: L0=64 jobs @64 steps, L1=256 @64, L2=256 @48.
  // CU c<64:      L2+L2+L2 = 144
  // CU [64,192):  L1+L1    = 128
  // CU [192,256): L2+L0    = 112
  GemmArgs ba;
  ba.L[0] = { G0, Wb0, mu0, nullptr, mu0, mb0, 4096, 1024, 1024, 2 };
  ba.L[1] = { G1, Wb1, mu1, e1,      mu1, mb1, 4096, 4096, 4096, 3 };
  ba.L[2] = { G2, Wb2, mu2, e2,      mu2, mb2, 3072, 4096, 4096, 3 };
  ba.seg[0] = { 0,   2, 0, 32 };   // L2 tm0-1:  64 jobs [0,64)
  ba.seg[1] = { 64,  1, 0, 32 };   // L1 tm0-3: 128 jobs [64,192)
  ba.seg[2] = { 192, 2, 6, 32 };   // L2 tm6-7:  64 jobs [192,256)
  ba.seg[3] = { 256, 2, 2, 32 };   // L2 tm2-3:  64 jobs [256,320)
  ba.seg[4] = { 320, 1, 4, 32 };   // L1 tm4-7: 128 jobs [320,448)
  ba.seg[5] = { 448, 0, 0, 8 };    // L0 tm0-7:  64 jobs [448,512)
  ba.seg[6] = { 512, 2, 4, 32 };   // L2 tm4-5:  64 jobs [512,576)
  ba.seg[7] = SENT;
  const int bwdBlocks = 576;

  // ---- iterate ----
  for (int it = 0; it < n_iters; ++it) {
    gemm_merged<<<fwdBlocks, 512, 0, stream>>>(fa);
    gemm_merged<<<bwdBlocks, 512, 0, stream>>>(ba);
  }
  // final prediction/error pass + e0 = mu0
  gemm_merged<<<fwdBlocks, 512, 0, stream>>>(faF);
  copy_e0<<<(512 * 1024 + 255) / 256, 256, 0, stream>>>(mu0, out);
}

// Round 16
// 2222.296 us; speedup vs baseline: 3.2290x; 1.1258x over previous
//
#include <hip/hip_runtime.h>
#include <hip/hip_bf16.h>
#include <hip/hip_fp8.h>
#include <stdint.h>

typedef __hip_bfloat16 bf16_t;
typedef __attribute__((ext_vector_type(8))) short bf16x8;
typedef __attribute__((ext_vector_type(4))) float f32x4;

#define MU_DT 0.01f
#define S8 8.0f                  // fp8 operand pre-scale (escape subnormals)
#define INV_S64 (1.0f / 64.0f)   // descale after fp8xfp8 GEMM

__device__ inline uint8_t f2fp8(float x) {
  __hip_fp8_e4m3 t(x);           // OCP e4m3 on gfx950
  return t.__x;
}

__device__ inline void gload_lds16(const void* g, void* lds) {
  __builtin_amdgcn_global_load_lds((const __attribute__((address_space(1))) void*)g,
                                   (__attribute__((address_space(3))) void*)lds, 16, 0, 0);
}

struct Seg { int start, layer, tmBase, tilesN; };

// ======================= fp8 iteration kernel =======================
// mode: 0 fwd tanh, 1 fwd identity, 2 bwd layer0, 3 bwd layer>0.
// All fp8 operands are pre-scaled x8; epilogue multiplies acc by 1/64.
struct GemmLayer8 {
  const uint8_t* A;    // (512 x K) fp8(x8), row-major
  const uint8_t* Bt;   // (N x K) fp8(x8), row-major
  const float*  X;     // fwd: mu_{l+1}/img (f32); bwd: mu_l (f32)
  const float*  E;     // bwd l>0: e_l
  float*        O1;    // fwd: e out; bwd: mu out (f32 master)
  uint8_t*      O2a;   // fwd: G8 out; bwd: m8 out (fp8 x8)
  bf16_t*       O2b;   // bwd: mb out (bf16, for final pass)
  int K, N, mode;
};
struct GemmArgs8 { GemmLayer8 L[3]; Seg seg[8]; };

// Engine = R15 geometry with BK=128 (fp8 rows are 128B like bf16 BK=64):
// BM=64 x BN=128, 8 waves, wave 32x32, dbuf 48KiB, issue-next-first +
// ONE __syncthreads per K-step. Staged bytes per job HALVED vs bf16.
// Swizzle identical (16B slots, slot ^= row&7, both sides). Cohort reads
// are ds_read_b64: 8 slots x 2 rows -> 2-way (free, m136).
__global__ __launch_bounds__(512) void gemm_fp8(GemmArgs8 args) {
  __shared__ __align__(16) uint8_t As[2 * 64 * 128];    // 2 x 8 KiB
  __shared__ __align__(16) uint8_t Bs[2 * 128 * 128];   // 2 x 16 KiB

  const int bid = blockIdx.x;
  int s = 0;
#pragma unroll
  for (int i = 1; i < 8; ++i)
    if (bid >= args.seg[i].start) s = i;
  const Seg sg = args.seg[s];
  const GemmLayer8 Lr = args.L[sg.layer];
  const int local = bid - sg.start;
  const int tm = sg.tmBase + local / sg.tilesN;
  const int tn = local % sg.tilesN;
  const int K = Lr.K;
  const int rowBase = tm * 64;
  const int colBase = tn * 128;

  const int tid  = threadIdx.x;
  const int lane = tid & 63;
  const int wv   = tid >> 6;
  const int wrM  = wv >> 2;            // 0..1 -> 32-row band
  const int wcN  = wv & 3;             // 0..3 -> 32-col band
  const int lo   = lane & 15, hi = lane >> 4;

  f32x4 acc[2][2];
#pragma unroll
  for (int m = 0; m < 2; ++m)
#pragma unroll
    for (int n = 0; n < 2; ++n)
      acc[m][n] = f32x4{0.f, 0.f, 0.f, 0.f};

  char* AsB = (char*)As;   // halves at +0 / +8192
  char* BsB = (char*)Bs;   // halves at +0 / +16384

  // staging: per 16B-chunk c -> (row = c>>3, slot = c&7), elements = bytes
  const uint8_t* pA0;
  const uint8_t* pB[2];
  {
    const int c = tid;
    const int r = c >> 3, sw = (c & 7) ^ (r & 7);
    pA0 = Lr.A + (size_t)(rowBase + r) * K + sw * 16;
  }
#pragma unroll
  for (int j = 0; j < 2; ++j) {
    const int c = j * 512 + tid;
    const int r = c >> 3, sw = (c & 7) ^ (r & 7);
    pB[j] = Lr.Bt + (size_t)(colBase + r) * K + sw * 16;
  }

  // read-side: frag (m|n, kk): k = kk*32 + hi*8 (slot = kk*2 + hi/2, half = hi&1)
  int aoff[2][4], boff[2][4];
#pragma unroll
  for (int m = 0; m < 2; ++m) {
    const int row = wrM * 32 + m * 16 + lo;
#pragma unroll
    for (int kk = 0; kk < 4; ++kk)
      aoff[m][kk] = row * 128 + (((kk * 2 + (hi >> 1)) ^ (row & 7)) << 4) + ((hi & 1) << 3);
  }
#pragma unroll
  for (int n = 0; n < 2; ++n) {
    const int row = wcN * 32 + n * 16 + lo;
#pragma unroll
    for (int kk = 0; kk < 4; ++kk)
      boff[n][kk] = row * 128 + (((kk * 2 + (hi >> 1)) ^ (row & 7)) << 4) + ((hi & 1) << 3);
  }

  const int waveB = wv * 1024;
  const int nkt = K >> 7;   // BK=128

  gload_lds16(pA0,   AsB + waveB);
  gload_lds16(pB[0], BsB + waveB);
  gload_lds16(pB[1], BsB + 8192 + waveB);
  __syncthreads();

  int cur = 0;
  for (int kt = 0; kt < nkt; ++kt) {
    const int curA = cur * 8192, curB = cur * 16384;
    if (kt + 1 < nkt) {
      const int ke = (kt + 1) * 128;
      gload_lds16(pA0 + ke,   AsB + (curA ^ 8192) + waveB);
      gload_lds16(pB[0] + ke, BsB + (curB ^ 16384) + waveB);
      gload_lds16(pB[1] + ke, BsB + (curB ^ 16384) + 8192 + waveB);
    }

    long a[2][4], b[2][4];
#pragma unroll
    for (int m = 0; m < 2; ++m)
#pragma unroll
      for (int kk = 0; kk < 4; ++kk)
        a[m][kk] = *(const long*)(AsB + curA + aoff[m][kk]);
#pragma unroll
    for (int n = 0; n < 2; ++n)
#pragma unroll
      for (int kk = 0; kk < 4; ++kk)
        b[n][kk] = *(const long*)(BsB + curB + boff[n][kk]);

#pragma unroll
    for (int kk = 0; kk < 4; ++kk)
#pragma unroll
      for (int m = 0; m < 2; ++m)
#pragma unroll
        for (int n = 0; n < 2; ++n)
          acc[m][n] = __builtin_amdgcn_mfma_f32_16x16x32_fp8_fp8(a[m][kk], b[n][kk], acc[m][n], 0, 0, 0);

    if (kt + 1 < nkt) {
      __syncthreads();
      cur ^= 1;
    }
  }

  // epilogue — C/D layout: col = lane&15, row = (lane>>4)*4 + reg
  const int N = Lr.N;
#pragma unroll
  for (int m = 0; m < 2; ++m) {
#pragma unroll
    for (int n = 0; n < 2; ++n) {
#pragma unroll
      for (int r = 0; r < 4; ++r) {
        const int row = rowBase + wrM * 32 + m * 16 + hi * 4 + r;
        const int col = colBase + wcN * 32 + n * 16 + lo;
        const float v = acc[m][n][r] * INV_S64;
        const size_t iN = (size_t)row * N + col;
        if (Lr.mode == 0) {
          const float mu = Lr.X[iN];
          const float t  = tanhf(v);
          const float e  = mu - t;
          Lr.O1[iN]  = e;
          Lr.O2a[iN] = f2fp8(e * (1.0f - t * t) * S8);
        } else if (Lr.mode == 1) {
          const float e = Lr.X[iN] - v;
          Lr.O1[iN]  = e;
          Lr.O2a[iN] = f2fp8(e * S8);
        } else {
          const float mu = Lr.X[iN];
          const float sub = (Lr.mode == 2) ? mu : Lr.E[iN];
          const float nv = mu + MU_DT * (v - sub);
          Lr.O1[iN]  = nv;
          Lr.O2a[iN] = f2fp8(nv * S8);
          Lr.O2b[iN] = __float2bfloat16(nv);
        }
      }
    }
  }
}

// ======================= bf16 final-pass kernel (R15 verbatim) =======================
struct GemmLayer {
  const bf16_t* A;
  const bf16_t* Bt;
  const float*  X;
  const float*  E;
  float*        O1;
  bf16_t*       O2;
  int K, N, ostride, mode;
};
struct GemmArgs { GemmLayer L[3]; Seg seg[8]; };

__global__ __launch_bounds__(512) void gemm_bf16(GemmArgs args) {
  __shared__ __align__(16) bf16_t As[2 * 64 * 64];
  __shared__ __align__(16) bf16_t Bs[2 * 128 * 64];

  const int bid = blockIdx.x;
  int s = 0;
#pragma unroll
  for (int i = 1; i < 8; ++i)
    if (bid >= args.seg[i].start) s = i;
  const Seg sg = args.seg[s];
  const GemmLayer Lr = args.L[sg.layer];
  const int local = bid - sg.start;
  const int tm = sg.tmBase + local / sg.tilesN;
  const int tn = local % sg.tilesN;
  const int K = Lr.K;
  const int rowBase = tm * 64;
  const int colBase = tn * 128;

  const int tid  = threadIdx.x;
  const int lane = tid & 63;
  const int wv   = tid >> 6;
  const int wrM  = wv >> 2;
  const int wcN  = wv & 3;
  const int lo   = lane & 15, hi = lane >> 4;

  f32x4 acc[2][2];
#pragma unroll
  for (int m = 0; m < 2; ++m)
#pragma unroll
    for (int n = 0; n < 2; ++n)
      acc[m][n] = f32x4{0.f, 0.f, 0.f, 0.f};

  char* AsB = (char*)As;
  char* BsB = (char*)Bs;

  const bf16_t* pA0;
  const bf16_t* pB[2];
  {
    const int c = tid;
    const int r = c >> 3, sw = (c & 7) ^ (r & 7);
    pA0 = Lr.A + (size_t)(rowBase + r) * K + sw * 8;
  }
#pragma unroll
  for (int j = 0; j < 2; ++j) {
    const int c = j * 512 + tid;
    const int r = c >> 3, sw = (c & 7) ^ (r & 7);
    pB[j] = Lr.Bt + (size_t)(colBase + r) * K + sw * 8;
  }

  int aoff[2][2], boff[2][2];
#pragma unroll
  for (int m = 0; m < 2; ++m) {
    const int row = wrM * 32 + m * 16 + lo;
#pragma unroll
    for (int kk = 0; kk < 2; ++kk)
      aoff[m][kk] = row * 128 + (((kk * 4 + hi) ^ (row & 7)) << 4);
  }
#pragma unroll
  for (int n = 0; n < 2; ++n) {
    const int row = wcN * 32 + n * 16 + lo;
#pragma unroll
    for (int kk = 0; kk < 2; ++kk)
      boff[n][kk] = row * 128 + (((kk * 4 + hi) ^ (row & 7)) << 4);
  }

  const int waveB = wv * 1024;
  const int nkt = K >> 6;

  gload_lds16(pA0,   AsB + waveB);
  gload_lds16(pB[0], BsB + waveB);
  gload_lds16(pB[1], BsB + 8192 + waveB);
  __syncthreads();

  int cur = 0;
  for (int kt = 0; kt < nkt; ++kt) {
    const int curA = cur * 8192, curB = cur * 16384;
    if (kt + 1 < nkt) {
      const int ke = (kt + 1) * 64;
      gload_lds16(pA0 + ke,   AsB + (curA ^ 8192) + waveB);
      gload_lds16(pB[0] + ke, BsB + (curB ^ 16384) + waveB);
      gload_lds16(pB[1] + ke, BsB + (curB ^ 16384) + 8192 + waveB);
    }

    bf16x8 a[2][2], b[2][2];
#pragma unroll
    for (int m = 0; m < 2; ++m)
#pragma unroll
      for (int kk = 0; kk < 2; ++kk)
        a[m][kk] = *(const bf16x8*)(AsB + curA + aoff[m][kk]);
#pragma unroll
    for (int n = 0; n < 2; ++n)
#pragma unroll
      for (int kk = 0; kk < 2; ++kk)
        b[n][kk] = *(const bf16x8*)(BsB + curB + boff[n][kk]);

#pragma unroll
    for (int kk = 0; kk < 2; ++kk)
#pragma unroll
      for (int m = 0; m < 2; ++m)
#pragma unroll
        for (int n = 0; n < 2; ++n)
          acc[m][n] = __builtin_amdgcn_mfma_f32_16x16x32_bf16(a[m][kk], b[n][kk], acc[m][n], 0, 0, 0);

    if (kt + 1 < nkt) {
      __syncthreads();
      cur ^= 1;
    }
  }

  const int N = Lr.N;
#pragma unroll
  for (int m = 0; m < 2; ++m) {
#pragma unroll
    for (int n = 0; n < 2; ++n) {
#pragma unroll
      for (int r = 0; r < 4; ++r) {
        const int row = rowBase + wrM * 32 + m * 16 + hi * 4 + r;
        const int col = colBase + wcN * 32 + n * 16 + lo;
        const float v = acc[m][n][r];
        const size_t iN = (size_t)row * N + col;
        const size_t iO = (size_t)row * Lr.ostride + col;
        if (Lr.mode == 0) {
          const float mu = Lr.X[iN];
          const float t  = tanhf(v);
          const float e  = mu - t;
          Lr.O1[iO] = e;
          Lr.O2[iN] = __float2bfloat16(e * (1.0f - t * t));
        } else if (Lr.mode == 1) {
          const float e = Lr.X[iN] - v;
          Lr.O1[iO] = e;
          Lr.O2[iN] = __float2bfloat16(e);
        }
      }
    }
  }
}

// ======================= prep kernels =======================
// W (R x C f32) -> WTb (C x R bf16), W8 (R x C fp8 x8), WT8 (C x R fp8 x8)
__global__ void prep_all(const float* __restrict__ W, bf16_t* __restrict__ WTb,
                         uint8_t* __restrict__ W8, uint8_t* __restrict__ WT8,
                         int R, int C) {
  __shared__ float t[64][65];
  const int tx = threadIdx.x, ty = threadIdx.y;  // (64,4)
  const int c0 = blockIdx.x * 64, r0 = blockIdx.y * 64;
  for (int rr = ty; rr < 64; rr += 4) {
    const float v = W[(size_t)(r0 + rr) * C + c0 + tx];
    W8[(size_t)(r0 + rr) * C + c0 + tx] = f2fp8(v * S8);
    t[rr][tx] = v;
  }
  __syncthreads();
  for (int rr = ty; rr < 64; rr += 4) {
    const float v = t[tx][rr];
    WTb[(size_t)(c0 + rr) * R + r0 + tx] = __float2bfloat16(v);
    WT8[(size_t)(c0 + rr) * R + r0 + tx] = f2fp8(v * S8);
  }
}

__global__ void copy_cast3(const float* __restrict__ in, float* __restrict__ of,
                           uint8_t* __restrict__ o8, bf16_t* __restrict__ ob, int n) {
  const int i = blockIdx.x * blockDim.x + threadIdx.x;
  if (i < n) {
    const float v = in[i];
    of[i] = v;
    o8[i] = f2fp8(v * S8);
    ob[i] = __float2bfloat16(v);
  }
}

__global__ void copy_e0(const float* __restrict__ mu0, float* __restrict__ out) {
  const int i = blockIdx.x * blockDim.x + threadIdx.x;
  if (i < 512 * 1024) {
    const int b = i >> 10, j = i & 1023;
    out[(size_t)b * 12288 + j] = mu0[i];
  }
}

extern "C" void kernel_launch(void* const* d_in, const int* in_sizes, int n_in,
                              void* d_out, int out_size, void* d_ws, size_t ws_size,
                              hipStream_t stream) {
  const float* img  = (const float*)d_in[0];
  const float* mu0i = (const float*)d_in[1];
  const float* mu1i = (const float*)d_in[2];
  const float* mu2i = (const float*)d_in[3];
  const float* W0   = (const float*)d_in[4];
  const float* W1   = (const float*)d_in[5];
  const float* W2   = (const float*)d_in[6];
  float* out = (float*)d_out;
  const int n_iters = 20;  // fixed by setup_inputs

  // ---- workspace carve ----
  char* p = (char*)d_ws;
  auto alloc = [&](size_t bytes) -> char* {
    char* r = p;
    p += (bytes + 255) & ~(size_t)255;
    return r;
  };
  // bf16 (final pass)
  bf16_t* WT0 = (bf16_t*)alloc((size_t)4096 * 1024 * 2);
  bf16_t* WT1 = (bf16_t*)alloc((size_t)4096 * 4096 * 2);
  bf16_t* WT2 = (bf16_t*)alloc((size_t)3072 * 4096 * 2);
  // fp8 weights (x8): row-major (bwd) + transposed (fwd)
  uint8_t* W80  = (uint8_t*)alloc((size_t)1024 * 4096);
  uint8_t* W81  = (uint8_t*)alloc((size_t)4096 * 4096);
  uint8_t* W82  = (uint8_t*)alloc((size_t)4096 * 3072);
  uint8_t* WT80 = (uint8_t*)alloc((size_t)4096 * 1024);
  uint8_t* WT81 = (uint8_t*)alloc((size_t)4096 * 4096);
  uint8_t* WT82 = (uint8_t*)alloc((size_t)3072 * 4096);
  // mus: f32 master + fp8(x8) + bf16
  float*   mu0 = (float*)alloc((size_t)512 * 1024 * 4);
  float*   mu1 = (float*)alloc((size_t)512 * 4096 * 4);
  float*   mu2 = (float*)alloc((size_t)512 * 4096 * 4);
  uint8_t* m80 = (uint8_t*)alloc((size_t)512 * 1024);
  uint8_t* m81 = (uint8_t*)alloc((size_t)512 * 4096);
  uint8_t* m82 = (uint8_t*)alloc((size_t)512 * 4096);
  bf16_t*  mb0 = (bf16_t*)alloc((size_t)512 * 1024 * 2);
  bf16_t*  mb1 = (bf16_t*)alloc((size_t)512 * 4096 * 2);
  bf16_t*  mb2 = (bf16_t*)alloc((size_t)512 * 4096 * 2);
  // errs f32, G fp8(x8), G bf16 (final-pass dump)
  float*   e1  = (float*)alloc((size_t)512 * 4096 * 4);
  float*   e2  = (float*)alloc((size_t)512 * 4096 * 4);
  float*   e3  = (float*)alloc((size_t)512 * 3072 * 4);
  uint8_t* G80 = (uint8_t*)alloc((size_t)512 * 4096);
  uint8_t* G81 = (uint8_t*)alloc((size_t)512 * 4096);
  uint8_t* G82 = (uint8_t*)alloc((size_t)512 * 3072);
  bf16_t*  Gb0 = (bf16_t*)alloc((size_t)512 * 4096 * 2);
  bf16_t*  Gb1 = (bf16_t*)alloc((size_t)512 * 4096 * 2);
  bf16_t*  Gb2 = (bf16_t*)alloc((size_t)512 * 3072 * 2);
  (void)ws_size;

  // ---- prep ----
  dim3 tb(64, 4);
  prep_all<<<dim3(4096 / 64, 1024 / 64), tb, 0, stream>>>(W0, WT0, W80, WT80, 1024, 4096);
  prep_all<<<dim3(4096 / 64, 4096 / 64), tb, 0, stream>>>(W1, WT1, W81, WT81, 4096, 4096);
  prep_all<<<dim3(3072 / 64, 4096 / 64), tb, 0, stream>>>(W2, WT2, W82, WT82, 4096, 3072);
  copy_cast3<<<(512 * 1024 + 255) / 256, 256, 0, stream>>>(mu0i, mu0, m80, mb0, 512 * 1024);
  copy_cast3<<<(512 * 4096 + 255) / 256, 256, 0, stream>>>(mu1i, mu1, m81, mb1, 512 * 4096);
  copy_cast3<<<(512 * 4096 + 255) / 256, 256, 0, stream>>>(mu2i, mu2, m82, mb2, 512 * 4096);

  const Seg SENT = { 1 << 30, 0, 0, 1 };

  // ---- fp8 forward (R15 fwd layout; steps halved uniformly) ----
  GemmArgs8 fa;
  fa.L[0] = { m80, WT80, mu1, nullptr, e1, G80, nullptr, 1024, 4096, 0 };
  fa.L[1] = { m81, WT81, mu2, nullptr, e2, G81, nullptr, 4096, 4096, 0 };
  fa.L[2] = { m82, WT82, img, nullptr, e3, G82, nullptr, 4096, 3072, 1 };
  fa.seg[0] = { 0,   0, 0, 32 };
  fa.seg[1] = { 256, 1, 0, 32 };
  fa.seg[2] = { 512, 2, 0, 24 };
  fa.seg[3] = SENT; fa.seg[4] = SENT; fa.seg[5] = SENT;
  fa.seg[6] = SENT; fa.seg[7] = SENT;
  const int fwdBlocks = 704;

  // ---- fp8 backward (R15 balanced layout) ----
  GemmArgs8 ba;
  ba.L[0] = { G80, W80, mu0, nullptr, mu0, m80, mb0, 4096, 1024, 2 };
  ba.L[1] = { G81, W81, mu1, e1,      mu1, m81, mb1, 4096, 4096, 3 };
  ba.L[2] = { G82, W82, mu2, e2,      mu2, m82, mb2, 3072, 4096, 3 };
  ba.seg[0] = { 0,   2, 0, 32 };
  ba.seg[1] = { 64,  1, 0, 32 };
  ba.seg[2] = { 192, 2, 6, 32 };
  ba.seg[3] = { 256, 2, 2, 32 };
  ba.seg[4] = { 320, 1, 4, 32 };
  ba.seg[5] = { 448, 0, 0, 8 };
  ba.seg[6] = { 512, 2, 4, 32 };
  ba.seg[7] = SENT;
  const int bwdBlocks = 576;

  // ---- bf16 final pass (errs straight into d_out, stride 12288) ----
  GemmArgs faF;
  faF.L[0] = { mb0, WT0, mu1, nullptr, out + 1024, Gb0, 1024, 4096, 12288, 0 };
  faF.L[1] = { mb1, WT1, mu2, nullptr, out + 5120, Gb1, 4096, 4096, 12288, 0 };
  faF.L[2] = { mb2, WT2, img, nullptr, out + 9216, Gb2, 4096, 3072, 12288, 1 };
  faF.seg[0] = { 0,   0, 0, 32 };
  faF.seg[1] = { 256, 1, 0, 32 };
  faF.seg[2] = { 512, 2, 0, 24 };
  faF.seg[3] = SENT; faF.seg[4] = SENT; faF.seg[5] = SENT;
  faF.seg[6] = SENT; faF.seg[7] = SENT;

  // ---- iterate ----
  for (int it = 0; it < n_iters; ++it) {
    gemm_fp8<<<fwdBlocks, 512, 0, stream>>>(fa);
    gemm_fp8<<<bwdBlocks, 512, 0, stream>>>(ba);
  }
  gemm_bf16<<<fwdBlocks, 512, 0, stream>>>(faF);
  copy_e0<<<(512 * 1024 + 255) / 256, 256, 0, stream>>>(mu0, out);
}